// Round 13
// baseline (730.324 us; speedup 1.0000x reference)
//
#include <hip/hip_runtime.h>
#include <hip/hip_bf16.h>
#include <math.h>

#define T_TOK 8192
#define DM 1024
#define DFF 4096
#define NE 8
#define HROWS 16512
#define MAX_TILES 136
#define TPX 17  // tiles per XCD class (MAX_TILES/8)

// prep_small block ranges
#define P_SPLIT 8192
#define P_TSW 1024
#define P_ZY 8193
#define P_ZLOG 64
#define P_ZMETA 1
#define NB_PREP (P_SPLIT + P_TSW + P_ZY + P_ZLOG + P_ZMETA)

// router_mega block ranges
#define R_ROUTER 512
#define R_TW1 32768
#define R_TW2 32768
#define NB_RMEGA (R_ROUTER + R_TW1 + R_TW2)

typedef __attribute__((ext_vector_type(8))) short bf16x8;
typedef __attribute__((ext_vector_type(4))) float f32x4;
typedef __attribute__((ext_vector_type(8))) _Float16 f16x8;
typedef __attribute__((ext_vector_type(4))) _Float16 f16x4;

__device__ __forceinline__ void async16(const void* g, void* l) {
  __builtin_amdgcn_global_load_lds((const __attribute__((address_space(1))) void*)g,
                                   (__attribute__((address_space(3))) void*)l, 16, 0, 0);
}

__device__ __forceinline__ unsigned short f2b(float f) {
  __hip_bfloat16 h = __float2bfloat16(f);
  return *reinterpret_cast<unsigned short*>(&h);
}

__device__ __forceinline__ float tanh_fast(float z) {
  return 1.f - 2.f / (__expf(2.f * z) + 1.f);
}

__device__ __forceinline__ float gelu_fast(float v) {
  float u = v + 0.044715f * v * v * v;
  return v / (1.f + __expf(-1.5957691216057308f * u));
}

// ---------------- prep_small: split x | split Wg1 | zero y/logits/meta ----------------
__global__ __launch_bounds__(256) void prep_small_kernel(
    const float* __restrict__ x, unsigned short* __restrict__ xb,
    _Float16* __restrict__ xh, _Float16* __restrict__ xl,
    const float* __restrict__ Wg1, _Float16* __restrict__ wth, _Float16* __restrict__ wtl,
    float* __restrict__ y, int out_size, float* __restrict__ logits, int* __restrict__ meta) {
  __shared__ float tile[32][33];
  const int b = blockIdx.x;
  const int tid = threadIdx.x;

  if (b < P_SPLIT) {
    int i = b * 256 + tid;
    float4 v = reinterpret_cast<const float4*>(x)[i];
    ushort4 ob;
    f16x4 oh, ol;
    float f, hf;
    f = v.x; oh[0] = (_Float16)f; hf = (float)oh[0]; ol[0] = (_Float16)((f - hf) * 2048.0f); ob.x = f2b(f);
    f = v.y; oh[1] = (_Float16)f; hf = (float)oh[1]; ol[1] = (_Float16)((f - hf) * 2048.0f); ob.y = f2b(f);
    f = v.z; oh[2] = (_Float16)f; hf = (float)oh[2]; ol[2] = (_Float16)((f - hf) * 2048.0f); ob.z = f2b(f);
    f = v.w; oh[3] = (_Float16)f; hf = (float)oh[3]; ol[3] = (_Float16)((f - hf) * 2048.0f); ob.w = f2b(f);
    reinterpret_cast<ushort4*>(xb)[i] = ob;
    reinterpret_cast<f16x4*>(xh)[i] = oh;
    reinterpret_cast<f16x4*>(xl)[i] = ol;
    return;
  }

  if (b < P_SPLIT + P_TSW) {
    int idx = b - P_SPLIT;
    int by = idx >> 5, bx = idx & 31;
    int r0 = by * 32, c0 = bx * 32;
    const int tx = tid & 31, ty = tid >> 5;
#pragma unroll
    for (int i = 0; i < 32; i += 8) tile[ty + i][tx] = Wg1[(size_t)(r0 + ty + i) * DM + c0 + tx];
    __syncthreads();
#pragma unroll
    for (int i = 0; i < 32; i += 8) {
      float f = tile[tx][ty + i];
      _Float16 h = (_Float16)f;
      size_t idx2 = (size_t)(c0 + ty + i) * DM + r0 + tx;
      wth[idx2] = h;
      wtl[idx2] = (_Float16)((f - (float)h) * 2048.0f);
    }
    return;
  }

  int zb = b - (P_SPLIT + P_TSW);
  if (zb < P_ZY) {
    int i4 = zb * 256 + tid;
    if ((i4 + 1) * 4 <= out_size) {
      reinterpret_cast<float4*>(y)[i4] = make_float4(0.f, 0.f, 0.f, 0.f);
    } else {
#pragma unroll
      for (int k = 0; k < 4; k++) {
        int idx = i4 * 4 + k;
        if (idx < out_size) y[idx] = 0.f;
      }
    }
  } else if (zb < P_ZY + P_ZLOG) {
    int i4 = (zb - P_ZY) * 256 + tid;
    reinterpret_cast<float4*>(logits)[i4] = make_float4(0.f, 0.f, 0.f, 0.f);
  } else {
    if (tid < 16) meta[tid] = 0;
  }
}

// ---------------- router_mega: MFMA router (b<512) | W1 transpose | W2 transpose ----------------
__global__ __launch_bounds__(256) void router_mega_kernel(
    const _Float16* __restrict__ xh, const _Float16* __restrict__ xl,
    const _Float16* __restrict__ wth, const _Float16* __restrict__ wtl,
    const float* __restrict__ bg1, const float* __restrict__ Wg2,
    float* __restrict__ logits,
    const float* __restrict__ W1, unsigned short* __restrict__ w1t,
    const float* __restrict__ W2, unsigned short* __restrict__ w2t) {
  // manual LDS union: router needs 64KB (2 bufs) + 8KB lgt; transposes need 4.2KB
  __shared__ __align__(16) char smem[73728];
  const int b = blockIdx.x;
  const int tid = threadIdx.x;

  if (b >= R_ROUTER) {
    // ---- W1/W2 transpose+cast paths ----
    float (*tile)[33] = (float(*)[33])smem;
    const int tx = tid & 31, ty = tid >> 5;
    if (b < R_ROUTER + R_TW1) {
      int idx = b - R_ROUTER;
      int e = idx >> 12, rem = idx & 4095;
      int by = rem >> 7, bx = rem & 127;  // by: DM/32, bx: DFF/32
      int r0 = by * 32, c0 = bx * 32;
      const float* src = W1 + (size_t)e * DM * DFF;
      unsigned short* dst = w1t + (size_t)e * DM * DFF;
#pragma unroll
      for (int i = 0; i < 32; i += 8) tile[ty + i][tx] = src[(size_t)(r0 + ty + i) * DFF + c0 + tx];
      __syncthreads();
#pragma unroll
      for (int i = 0; i < 32; i += 8) dst[(size_t)(c0 + ty + i) * DM + r0 + tx] = f2b(tile[tx][ty + i]);
    } else {
      int idx = b - R_ROUTER - R_TW1;
      int e = idx >> 12, rem = idx & 4095;
      int by = rem >> 5, bx = rem & 31;  // by: DFF/32, bx: DM/32
      int r0 = by * 32, c0 = bx * 32;
      const float* src = W2 + (size_t)e * DFF * DM;
      unsigned short* dst = w2t + (size_t)e * DFF * DM;
#pragma unroll
      for (int i = 0; i < 32; i += 8) tile[ty + i][tx] = src[(size_t)(r0 + ty + i) * DM + c0 + tx];
      __syncthreads();
#pragma unroll
      for (int i = 0; i < 32; i += 8) dst[(size_t)(c0 + ty + i) * DFF + r0 + tx] = f2b(tile[tx][ty + i]);
    }
    return;
  }

  // ---- router path (round-11 verified body; flattened grid) ----
  float* lgt = (float*)(smem + 65536);  // [128][2][NE]
  const int lane = tid & 63;
  const int w = tid >> 6;
  const int n0 = (b & 7) * 128, m0 = (b >> 3) * 128;

  const int r0 = w * 16 + (lane >> 2);
  const int r1 = r0 + 64;
  const int sp = lane & 3;
  const int k0s = (sp ^ ((r0 >> 1) & 3)) * 8;
  const int k1s = (sp ^ ((r1 >> 1) & 3)) * 8;

  const _Float16* gAh0 = xh + (size_t)(m0 + r0) * DM + k0s;
  const _Float16* gAh1 = xh + (size_t)(m0 + r1) * DM + k1s;
  const _Float16* gAl0 = xl + (size_t)(m0 + r0) * DM + k0s;
  const _Float16* gAl1 = xl + (size_t)(m0 + r1) * DM + k1s;
  const _Float16* gBh0 = wth + (size_t)(n0 + r0) * DM + k0s;
  const _Float16* gBh1 = wth + (size_t)(n0 + r1) * DM + k1s;
  const _Float16* gBl0 = wtl + (size_t)(n0 + r0) * DM + k0s;
  const _Float16* gBl1 = wtl + (size_t)(n0 + r1) * DM + k1s;

  const int wr = (w >> 1) * 64, wc = (w & 1) * 64;
  const int l15 = lane & 15, ls = lane >> 4;

  f32x4 zero = {0.f, 0.f, 0.f, 0.f};
  f32x4 acc_hh[4][4], acc_c[4][4];
#pragma unroll
  for (int i = 0; i < 4; i++)
#pragma unroll
    for (int j = 0; j < 4; j++) { acc_hh[i][j] = zero; acc_c[i][j] = zero; }

  auto stage = [&](int buf, int kt) {
    char* bb = smem + buf * 32768 + w * 1024;
    async16(gAh0 + kt, bb);
    async16(gAh1 + kt, bb + 4096);
    async16(gAl0 + kt, bb + 8192);
    async16(gAl1 + kt, bb + 8192 + 4096);
    async16(gBh0 + kt, bb + 16384);
    async16(gBh1 + kt, bb + 16384 + 4096);
    async16(gBl0 + kt, bb + 24576);
    async16(gBl1 + kt, bb + 24576 + 4096);
  };
  auto computeTile = [&](int cur) {
    const char* base = smem + cur * 32768;
    f16x8 ah[4], bh[4], tmp[4];
#pragma unroll
    for (int i = 0; i < 4; i++) {
      int ar = wr + i * 16 + l15;
      ah[i] = *(const f16x8*)(base + ar * 64 + ((ls ^ ((ar >> 1) & 3)) << 4));
    }
#pragma unroll
    for (int j = 0; j < 4; j++) {
      int br = wc + j * 16 + l15;
      bh[j] = *(const f16x8*)(base + 16384 + br * 64 + ((ls ^ ((br >> 1) & 3)) << 4));
    }
    __builtin_amdgcn_s_setprio(1);
#pragma unroll
    for (int i = 0; i < 4; i++)
#pragma unroll
      for (int j = 0; j < 4; j++)
        acc_hh[i][j] = __builtin_amdgcn_mfma_f32_16x16x32_f16(ah[i], bh[j], acc_hh[i][j], 0, 0, 0);
    __builtin_amdgcn_s_setprio(0);
#pragma unroll
    for (int j = 0; j < 4; j++) {
      int br = wc + j * 16 + l15;
      tmp[j] = *(const f16x8*)(base + 24576 + br * 64 + ((ls ^ ((br >> 1) & 3)) << 4));
    }
    __builtin_amdgcn_s_setprio(1);
#pragma unroll
    for (int i = 0; i < 4; i++)
#pragma unroll
      for (int j = 0; j < 4; j++)
        acc_c[i][j] = __builtin_amdgcn_mfma_f32_16x16x32_f16(ah[i], tmp[j], acc_c[i][j], 0, 0, 0);
    __builtin_amdgcn_s_setprio(0);
#pragma unroll
    for (int i = 0; i < 4; i++) {
      int ar = wr + i * 16 + l15;
      tmp[i] = *(const f16x8*)(base + 8192 + ar * 64 + ((ls ^ ((ar >> 1) & 3)) << 4));
    }
    __builtin_amdgcn_s_setprio(1);
#pragma unroll
    for (int i = 0; i < 4; i++)
#pragma unroll
      for (int j = 0; j < 4; j++)
        acc_c[i][j] = __builtin_amdgcn_mfma_f32_16x16x32_f16(tmp[i], bh[j], acc_c[i][j], 0, 0, 0);
    __builtin_amdgcn_s_setprio(0);
  };

  const int NIT = DM / 32;
  stage(0, 0);
  __syncthreads();
#pragma unroll 2
  for (int t = 0; t < NIT - 1; t++) {
    const int cur = t & 1;
    stage(cur ^ 1, (t + 1) * 32);
    computeTile(cur);
    __syncthreads();
  }
  computeTile((NIT - 1) & 1);

  float w2r[4][8];
  float bias[4];
#pragma unroll
  for (int j = 0; j < 4; j++) {
    int gn = n0 + wc + j * 16 + l15;
    bias[j] = bg1[gn];
    float4 u = *(const float4*)(Wg2 + (size_t)gn * NE);
    float4 v = *(const float4*)(Wg2 + (size_t)gn * NE + 4);
    w2r[j][0] = u.x; w2r[j][1] = u.y; w2r[j][2] = u.z; w2r[j][3] = u.w;
    w2r[j][4] = v.x; w2r[j][5] = v.y; w2r[j][6] = v.z; w2r[j][7] = v.w;
  }
  const float inv2k = 1.0f / 2048.0f;
  const int half = wc >> 6;
  const bool b3 = (l15 & 8) != 0, b2 = (l15 & 4) != 0, b1 = (l15 & 2) != 0;
#pragma unroll
  for (int i = 0; i < 4; i++) {
#pragma unroll
    for (int r = 0; r < 4; r++) {
      float s[8] = {0.f, 0.f, 0.f, 0.f, 0.f, 0.f, 0.f, 0.f};
#pragma unroll
      for (int j = 0; j < 4; j++) {
        float hv = tanh_fast(acc_hh[i][j][r] + acc_c[i][j][r] * inv2k + bias[j]);
#pragma unroll
        for (int e = 0; e < NE; e++) s[e] = fmaf(hv, w2r[j][e], s[e]);
      }
      float t4_[4], t2_[2], t1_;
#pragma unroll
      for (int q = 0; q < 4; q++) {
        float snd = b3 ? s[q] : s[q + 4];
        float rcv = __shfl_xor(snd, 8);
        t4_[q] = (b3 ? s[q + 4] : s[q]) + rcv;
      }
#pragma unroll
      for (int q = 0; q < 2; q++) {
        float snd = b2 ? t4_[q] : t4_[q + 2];
        float rcv = __shfl_xor(snd, 4);
        t2_[q] = (b2 ? t4_[q + 2] : t4_[q]) + rcv;
      }
      {
        float snd = b1 ? t2_[0] : t2_[1];
        float rcv = __shfl_xor(snd, 2);
        t1_ = (b1 ? t2_[1] : t2_[0]) + rcv;
      }
      t1_ += __shfl_xor(t1_, 1);
      int m = wr + i * 16 + ls * 4 + r;
      if (!(l15 & 1)) lgt[m * (2 * NE) + half * NE + (l15 >> 1)] = t1_;
    }
  }
  __syncthreads();
#pragma unroll
  for (int q = 0; q < 4; q++) {
    int idx = tid * 4 + q;
    int m = idx >> 3, e = idx & 7;
    float v = lgt[m * (2 * NE) + e] + lgt[m * (2 * NE) + NE + e];
    atomicAdd(&logits[(size_t)(m0 + m) * NE + e], v);
  }
}

// ---------------- top-2 over 8 logits per token ----------------
__global__ __launch_bounds__(256) void topk_small_kernel(
    const float* __restrict__ logits, int* __restrict__ tIdx, float* __restrict__ tGate,
    int* __restrict__ counts) {
  __shared__ int lc[NE];
  const int tid = threadIdx.x;
  if (tid < NE) lc[tid] = 0;
  __syncthreads();
  int t = blockIdx.x * 256 + tid;
  float p[NE];
  float4 p0 = *(const float4*)(logits + (size_t)t * NE);
  float4 p1 = *(const float4*)(logits + (size_t)t * NE + 4);
  p[0] = p0.x; p[1] = p0.y; p[2] = p0.z; p[3] = p0.w;
  p[4] = p1.x; p[5] = p1.y; p[6] = p1.z; p[7] = p1.w;
  float v1 = -1e30f, v2 = -1e30f; int i1 = 0, i2 = 1;
#pragma unroll
  for (int e = 0; e < NE; e++) {
    float v = p[e];
    if (v > v1) { v2 = v1; i2 = i1; v1 = v; i1 = e; }
    else if (v > v2) { v2 = v; i2 = e; }
  }
  float mx = v1;
  float s = 0.f;
#pragma unroll
  for (int e = 0; e < NE; e++) s += __expf(p[e] - mx);
  float inv = 1.f / s;
  float g1 = __expf(p[i1] - mx) * inv;
  float g2 = __expf(p[i2] - mx) * inv;
  float den = 1.f / (g1 + g2 + 1e-6f);
  tIdx[2 * t] = i1; tIdx[2 * t + 1] = i2;
  tGate[2 * t] = g1 * den; tGate[2 * t + 1] = g2 * den;
  atomicAdd(&lc[i1], 1);
  atomicAdd(&lc[i2], 1);
  __syncthreads();
  if (tid < NE) atomicAdd(&counts[tid], lc[tid]);
}

// ---------------- prefix sums + tile descriptors (single thread) ----------------
__global__ void build_tiles_kernel(const int* __restrict__ counts, int* __restrict__ offsets,
                                   int4* __restrict__ desc, int* __restrict__ nTiles) {
  if (threadIdx.x != 0 || blockIdx.x != 0) return;
  int off = 0, nt = 0;
  for (int e = 0; e < NE; e++) {
    offsets[e] = off;
    int c = counts[e];
    if (c < 0) c = 0;
    if (c > 2 * T_TOK) c = 2 * T_TOK;
    for (int r = 0; r < c && nt < MAX_TILES; r += 128) {
      int v = c - r; if (v > 128) v = 128;
      desc[nt++] = make_int4(e, off + r, v, 0);
    }
    off += c;
    if (off > 2 * T_TOK) off = 2 * T_TOK;
  }
  offsets[NE] = off;
  *nTiles = nt;
}

// ---------------- scatter tokens into expert-grouped lists ----------------
__global__ void scatter_kernel(const int* __restrict__ tIdx, const float* __restrict__ tGate,
                               const int* __restrict__ offsets, int* __restrict__ fill,
                               int* __restrict__ tokList, float* __restrict__ gateList) {
  int id = blockIdx.x * blockDim.x + threadIdx.x;
  if (id >= 2 * T_TOK) return;
  int e = tIdx[id] & 7;
  int pos = atomicAdd(&fill[e], 1);
  int row = offsets[e] + pos;
  if (row < 0 || row >= 2 * T_TOK) return;
  tokList[row] = id >> 1;
  gateList[row] = tGate[id];
}

// ---------------- FFN1: h = gelu(gather(xb) @ W1_e), BK=32, 3-buf counted-vmcnt, XCD-affine ----------------
__global__ __launch_bounds__(256) void ffn1_kernel(
    const unsigned short* __restrict__ xb, const unsigned short* __restrict__ w1t,
    const int* __restrict__ tokList, const int4* __restrict__ desc,
    const int* __restrict__ nTiles, unsigned short* __restrict__ h) {
  const int g = blockIdx.x;
  const int tileIdx = (g & 7) * TPX + ((g >> 3) % TPX);
  const int nb = g / (8 * TPX);
  if (tileIdx >= *nTiles) return;
  int4 d = desc[tileIdx];
  const int e = d.x, rowStart = d.y, valid = d.z;
  const int n0 = nb * 128;

  __shared__ __align__(16) char AB[3][16384];

  const int tid = threadIdx.x;
  const int lane = tid & 63;
  const int w = tid >> 6;

  const int r0 = w * 16 + (lane >> 2);
  const int r1 = r0 + 64;
  const int sp = lane & 3;
  const int k0s = (sp ^ ((r0 >> 1) & 3)) * 8;
  const int k1s = (sp ^ ((r1 >> 1) & 3)) * 8;

  const unsigned short* gA0 = xb + (size_t)(tokList[rowStart + r0] & (T_TOK - 1)) * DM + k0s;
  const unsigned short* gA1 = xb + (size_t)(tokList[rowStart + r1] & (T_TOK - 1)) * DM + k1s;
  const unsigned short* gB0 = w1t + ((size_t)e * DFF + n0 + r0) * DM + k0s;
  const unsigned short* gB1 = w1t + ((size_t)e * DFF + n0 + r1) * DM + k1s;

  const int wr = (w >> 1) * 64, wc = (w & 1) * 64;
  const int l15 = lane & 15, ls = lane >> 4;

  f32x4 zero = {0.f, 0.f, 0.f, 0.f};
  f32x4 acc[4][4];
#pragma unroll
  for (int i = 0; i < 4; i++)
#pragma unroll
    for (int j = 0; j < 4; j++) acc[i][j] = zero;

  auto stage = [&](int buf, int kt) {
    char* dA = &AB[buf][0] + w * 1024;
    char* dB = dA + 8192;
    async16(gA0 + kt, dA);
    async16(gA1 + kt, dA + 4096);
    async16(gB0 + kt, dB);
    async16(gB1 + kt, dB + 4096);
  };
  auto computeTile = [&](int cur) {
    const char* rA = &AB[cur][0];
    const char* rB = rA + 8192;
    bf16x8 af[4], bfv[4];
#pragma unroll
    for (int i = 0; i < 4; i++) {
      int ar = wr + i * 16 + l15;
      af[i] = *(const bf16x8*)(rA + ar * 64 + ((ls ^ ((ar >> 1) & 3)) << 4));
    }
#pragma unroll
    for (int j = 0; j < 4; j++) {
      int br = wc + j * 16 + l15;
      bfv[j] = *(const bf16x8*)(rB + br * 64 + ((ls ^ ((br >> 1) & 3)) << 4));
    }
    __builtin_amdgcn_s_setprio(1);
#pragma unroll
    for (int i = 0; i < 4; i++)
#pragma unroll
      for (int j = 0; j < 4; j++)
        acc[i][j] = __builtin_amdgcn_mfma_f32_16x16x32_bf16(af[i], bfv[j], acc[i][j], 0, 0, 0);
    __builtin_amdgcn_s_setprio(0);
  };

  const int NIT = DM / 32;
  stage(0, 0);
  stage(1, 32);
  int cur = 0, stg = 2;
  for (int t = 0; t < NIT; t++) {
    if (t < NIT - 1) asm volatile("s_waitcnt vmcnt(4)" ::: "memory");
    else             asm volatile("s_waitcnt vmcnt(0)" ::: "memory");
    __builtin_amdgcn_s_barrier();
    __builtin_amdgcn_sched_barrier(0);
    if (t < NIT - 2) {
      stage(stg, (t + 2) * 32);
      stg = (stg == 2) ? 0 : stg + 1;
    }
    computeTile(cur);
    cur = (cur == 2) ? 0 : cur + 1;
  }

#pragma unroll
  for (int i = 0; i < 4; i++) {
#pragma unroll
    for (int r = 0; r < 4; r++) {
      int m = wr + i * 16 + ls * 4 + r;
      if (m < valid) {
        size_t base = (size_t)(rowStart + m) * DFF + n0 + wc;
#pragma unroll
        for (int j = 0; j < 4; j++) {
          h[base + j * 16 + l15] = f2b(gelu_fast(acc[i][j][r]));
        }
      }
    }
  }
}

// ---------------- FFN2: y += gate * (h @ W2_e), BK=32, 3-buf counted-vmcnt, XCD-affine ----------------
__global__ __launch_bounds__(256) void ffn2_kernel(
    const unsigned short* __restrict__ h, const unsigned short* __restrict__ w2t,
    const int* __restrict__ tokList, const float* __restrict__ gateList,
    const int4* __restrict__ desc, const int* __restrict__ nTiles,
    float* __restrict__ y) {
  const int g = blockIdx.x;
  const int tileIdx = (g & 7) * TPX + ((g >> 3) % TPX);
  const int nb = g / (8 * TPX);
  if (tileIdx >= *nTiles) return;
  int4 d = desc[tileIdx];
  const int e = d.x, rowStart = d.y, valid = d.z;
  const int n0 = nb * 128;

  __shared__ __align__(16) char AB[3][16384];

  const int tid = threadIdx.x;
  const int lane = tid & 63;
  const int w = tid >> 6;

  const int r0 = w * 16 + (lane >> 2);
  const int r1 = r0 + 64;
  const int sp = lane & 3;
  const int k0s = (sp ^ ((r0 >> 1) & 3)) * 8;
  const int k1s = (sp ^ ((r1 >> 1) & 3)) * 8;

  const unsigned short* gA0 = h + (size_t)(rowStart + r0) * DFF + k0s;
  const unsigned short* gA1 = h + (size_t)(rowStart + r1) * DFF + k1s;
  const unsigned short* gB0 = w2t + ((size_t)e * DM + n0 + r0) * DFF + k0s;
  const unsigned short* gB1 = w2t + ((size_t)e * DM + n0 + r1) * DFF + k1s;

  const int wr = (w >> 1) * 64, wc = (w & 1) * 64;
  const int l15 = lane & 15, ls = lane >> 4;

  f32x4 zero = {0.f, 0.f, 0.f, 0.f};
  f32x4 acc[4][4];
#pragma unroll
  for (int i = 0; i < 4; i++)
#pragma unroll
    for (int j = 0; j < 4; j++) acc[i][j] = zero;

  auto stage = [&](int buf, int kt) {
    char* dA = &AB[buf][0] + w * 1024;
    char* dB = dA + 8192;
    async16(gA0 + kt, dA);
    async16(gA1 + kt, dA + 4096);
    async16(gB0 + kt, dB);
    async16(gB1 + kt, dB + 4096);
  };
  auto computeTile = [&](int cur) {
    const char* rA = &AB[cur][0];
    const char* rB = rA + 8192;
    bf16x8 af[4], bfv[4];
#pragma unroll
    for (int i = 0; i < 4; i++) {
      int ar = wr + i * 16 + l15;
      af[i] = *(const bf16x8*)(rA + ar * 64 + ((ls ^ ((ar >> 1) & 3)) << 4));
    }
#pragma unroll
    for (int j = 0; j < 4; j++) {
      int br = wc + j * 16 + l15;
      bfv[j] = *(const bf16x8*)(rB + br * 64 + ((ls ^ ((br >> 1) & 3)) << 4));
    }
    __builtin_amdgcn_s_setprio(1);
#pragma unroll
    for (int i = 0; i < 4; i++)
#pragma unroll
      for (int j = 0; j < 4; j++)
        acc[i][j] = __builtin_amdgcn_mfma_f32_16x16x32_bf16(af[i], bfv[j], acc[i][j], 0, 0, 0);
    __builtin_amdgcn_s_setprio(0);
  };

  const int NIT = DFF / 32;
  stage(0, 0);
  stage(1, 32);
  int cur = 0, stg = 2;
  for (int t = 0; t < NIT; t++) {
    if (t < NIT - 1) asm volatile("s_waitcnt vmcnt(4)" ::: "memory");
    else             asm volatile("s_waitcnt vmcnt(0)" ::: "memory");
    __builtin_amdgcn_s_barrier();
    __builtin_amdgcn_sched_barrier(0);
    if (t < NIT - 2) {
      stage(stg, (t + 2) * 32);
      stg = (stg == 2) ? 0 : stg + 1;
    }
    computeTile(cur);
    cur = (cur == 2) ? 0 : cur + 1;
  }

#pragma unroll
  for (int i = 0; i < 4; i++) {
#pragma unroll
    for (int r = 0; r < 4; r++) {
      int m = wr + i * 16 + ls * 4 + r;
      if (m < valid) {
        int row = rowStart + m;
        int tok = tokList[row] & (T_TOK - 1);
        float g2 = gateList[row];
        float* yr = y + (size_t)tok * DM + n0 + wc;
#pragma unroll
        for (int j = 0; j < 4; j++) {
          atomicAdd(&yr[j * 16 + l15], g2 * acc[i][j][r]);
        }
      }
    }
  }
}

// ---------------- host launch ----------------
extern "C" void kernel_launch(void* const* d_in, const int* in_sizes, int n_in,
                              void* d_out, int out_size, void* d_ws, size_t ws_size,
                              hipStream_t stream) {
  const float* x   = (const float*)d_in[0];
  const float* Wg1 = (const float*)d_in[1];
  const float* bg1 = (const float*)d_in[2];
  const float* Wg2 = (const float*)d_in[3];
  const float* W1  = (const float*)d_in[4];
  const float* W2  = (const float*)d_in[5];
  float* y = (float*)d_out;
  char* ws = (char*)d_ws;

  const size_t SZ_W1T = (size_t)NE * DFF * DM * 2;
  const size_t OFF_W1T = 0;
  const size_t OFF_W2T = OFF_W1T + SZ_W1T;
  const size_t OFF_XB  = OFF_W2T + SZ_W1T;
  const size_t OFF_H   = OFF_XB + (size_t)T_TOK * DM * 2;
  const size_t OFF_TOK = OFF_H + (size_t)HROWS * DFF * 2;
  const size_t OFF_GATE = OFF_TOK + (size_t)HROWS * 4;
  const size_t OFF_TIDX = OFF_GATE + (size_t)HROWS * 4;
  const size_t OFF_TG   = OFF_TIDX + (size_t)2 * T_TOK * 4;
  const size_t OFF_LOG  = OFF_TG + (size_t)2 * T_TOK * 4;
  const size_t OFF_META = OFF_LOG + (size_t)T_TOK * NE * 4;
  const size_t NEED = OFF_META + 4096;

  const size_t OFF_XH  = OFF_H;
  const size_t OFF_XL  = OFF_XH + (size_t)T_TOK * DM * 2;
  const size_t OFF_WTH = OFF_XL + (size_t)T_TOK * DM * 2;
  const size_t OFF_WTL = OFF_WTH + (size_t)DM * DM * 2;

  if (ws_size < NEED) {
    hipMemsetAsync(d_out, 0, (size_t)out_size * 4, stream);
    return;
  }

  unsigned short* w1t = (unsigned short*)(ws + OFF_W1T);
  unsigned short* w2t = (unsigned short*)(ws + OFF_W2T);
  unsigned short* xb  = (unsigned short*)(ws + OFF_XB);
  unsigned short* h   = (unsigned short*)(ws + OFF_H);
  _Float16* xh        = (_Float16*)(ws + OFF_XH);
  _Float16* xl        = (_Float16*)(ws + OFF_XL);
  _Float16* wth       = (_Float16*)(ws + OFF_WTH);
  _Float16* wtl       = (_Float16*)(ws + OFF_WTL);
  int* tokList        = (int*)(ws + OFF_TOK);
  float* gateList     = (float*)(ws + OFF_GATE);
  int* tIdx           = (int*)(ws + OFF_TIDX);
  float* tGate        = (float*)(ws + OFF_TG);
  float* logits       = (float*)(ws + OFF_LOG);
  int* meta           = (int*)(ws + OFF_META);
  int* counts         = (int*)(ws + OFF_META);
  int* fill           = (int*)(ws + OFF_META + 32);
  int* offsets        = (int*)(ws + OFF_META + 64);
  int* nTiles         = (int*)(ws + OFF_META + 128);
  int4* desc          = (int4*)(ws + OFF_META + 160);

  prep_small_kernel<<<dim3(NB_PREP), dim3(256), 0, stream>>>(
      x, xb, xh, xl, Wg1, wth, wtl, y, out_size, logits, meta);

  // router + W1/W2 transpose co-scheduled in one launch (transposes hide under router compute)
  router_mega_kernel<<<dim3(NB_RMEGA), dim3(256), 0, stream>>>(
      xh, xl, wth, wtl, bg1, Wg2, logits, W1, w1t, W2, w2t);

  topk_small_kernel<<<dim3(T_TOK / 256), dim3(256), 0, stream>>>(logits, tIdx, tGate, counts);
  build_tiles_kernel<<<dim3(1), dim3(64), 0, stream>>>(counts, offsets, desc, nTiles);
  scatter_kernel<<<dim3((2 * T_TOK) / 256), dim3(256), 0, stream>>>(tIdx, tGate, offsets, fill,
                                                                    tokList, gateList);

  ffn1_kernel<<<dim3((DFF / 128) * MAX_TILES), dim3(256), 0, stream>>>(xb, w1t, tokList, desc,
                                                                       nTiles, h);
  ffn2_kernel<<<dim3((DM / 128) * MAX_TILES), dim3(256), 0, stream>>>(h, w2t, tokList, gateList,
                                                                      desc, nTiles, y);
}

// Round 14
// 675.133 us; speedup vs baseline: 1.0817x; 1.0817x over previous
//
#include <hip/hip_runtime.h>
#include <hip/hip_bf16.h>
#include <math.h>

#define T_TOK 8192
#define DM 1024
#define DFF 4096
#define NE 8
#define HROWS 16512
#define MAX_TILES 136
#define TPX 17  // tiles per XCD class (MAX_TILES/8)

// fused-prep block ranges
#define NB_SPLIT (T_TOK * DM / 4 / 256)          // 8192
#define NB_TW1 ((DFF / 32) * (DM / 32) * NE)     // 32768
#define NB_TW2 ((DM / 32) * (DFF / 32) * NE)     // 32768
#define NB_TSW ((DM / 32) * (DM / 32))           // 1024
#define NB_ZY 8193                               // zero y + loss (out_size floats)
#define NB_ZLOG 64                               // zero logits (65536 floats)
#define NB_ZMETA 1
#define NB_PREP (NB_SPLIT + NB_TW1 + NB_TW2 + NB_TSW + NB_ZY + NB_ZLOG + NB_ZMETA)

typedef __attribute__((ext_vector_type(8))) short bf16x8;
typedef __attribute__((ext_vector_type(4))) float f32x4;
typedef __attribute__((ext_vector_type(8))) _Float16 f16x8;
typedef __attribute__((ext_vector_type(4))) _Float16 f16x4;

__device__ __forceinline__ void async16(const void* g, void* l) {
  __builtin_amdgcn_global_load_lds((const __attribute__((address_space(1))) void*)g,
                                   (__attribute__((address_space(3))) void*)l, 16, 0, 0);
}

__device__ __forceinline__ unsigned short f2b(float f) {
  __hip_bfloat16 h = __float2bfloat16(f);
  return *reinterpret_cast<unsigned short*>(&h);
}

__device__ __forceinline__ float tanh_fast(float z) {
  return 1.f - 2.f / (__expf(2.f * z) + 1.f);
}

__device__ __forceinline__ float gelu_fast(float v) {
  float u = v + 0.044715f * v * v * v;
  return v / (1.f + __expf(-1.5957691216057308f * u));
}

// ---------------- fused preprocessing + zero-init ----------------
__global__ __launch_bounds__(256) void prep_all_kernel(
    const float* __restrict__ x, unsigned short* __restrict__ xb,
    _Float16* __restrict__ xh, _Float16* __restrict__ xl,
    const float* __restrict__ W1, unsigned short* __restrict__ w1t,
    const float* __restrict__ W2, unsigned short* __restrict__ w2t,
    const float* __restrict__ Wg1, _Float16* __restrict__ wth, _Float16* __restrict__ wtl,
    float* __restrict__ y, int out_size, float* __restrict__ logits, int* __restrict__ meta) {
  __shared__ float tile[32][33];
  const int b = blockIdx.x;
  const int tid = threadIdx.x;

  if (b < NB_SPLIT) {
    int i = b * 256 + tid;
    float4 v = reinterpret_cast<const float4*>(x)[i];
    ushort4 ob;
    f16x4 oh, ol;
    float f, hf;
    f = v.x; oh[0] = (_Float16)f; hf = (float)oh[0]; ol[0] = (_Float16)((f - hf) * 2048.0f); ob.x = f2b(f);
    f = v.y; oh[1] = (_Float16)f; hf = (float)oh[1]; ol[1] = (_Float16)((f - hf) * 2048.0f); ob.y = f2b(f);
    f = v.z; oh[2] = (_Float16)f; hf = (float)oh[2]; ol[2] = (_Float16)((f - hf) * 2048.0f); ob.z = f2b(f);
    f = v.w; oh[3] = (_Float16)f; hf = (float)oh[3]; ol[3] = (_Float16)((f - hf) * 2048.0f); ob.w = f2b(f);
    reinterpret_cast<ushort4*>(xb)[i] = ob;
    reinterpret_cast<f16x4*>(xh)[i] = oh;
    reinterpret_cast<f16x4*>(xl)[i] = ol;
    return;
  }

  if (b >= NB_SPLIT + NB_TW1 + NB_TW2 + NB_TSW) {
    int zb = b - (NB_SPLIT + NB_TW1 + NB_TW2 + NB_TSW);
    if (zb < NB_ZY) {
      int i4 = zb * 256 + tid;
      if ((i4 + 1) * 4 <= out_size) {
        reinterpret_cast<float4*>(y)[i4] = make_float4(0.f, 0.f, 0.f, 0.f);
      } else {
#pragma unroll
        for (int k = 0; k < 4; k++) {
          int idx = i4 * 4 + k;
          if (idx < out_size) y[idx] = 0.f;
        }
      }
    } else if (zb < NB_ZY + NB_ZLOG) {
      int i4 = (zb - NB_ZY) * 256 + tid;
      reinterpret_cast<float4*>(logits)[i4] = make_float4(0.f, 0.f, 0.f, 0.f);
    } else {
      if (tid < 16) meta[tid] = 0;
    }
    return;
  }

  const int tx = tid & 31, ty = tid >> 5;  // (32,8)

  if (b < NB_SPLIT + NB_TW1) {
    int idx = b - NB_SPLIT;
    int e = idx >> 12, rem = idx & 4095;
    int by = rem >> 7, bx = rem & 127;
    int r0 = by * 32, c0 = bx * 32;
    const float* src = W1 + (size_t)e * DM * DFF;
    unsigned short* dst = w1t + (size_t)e * DM * DFF;
#pragma unroll
    for (int i = 0; i < 32; i += 8) tile[ty + i][tx] = src[(size_t)(r0 + ty + i) * DFF + c0 + tx];
    __syncthreads();
#pragma unroll
    for (int i = 0; i < 32; i += 8) dst[(size_t)(c0 + ty + i) * DM + r0 + tx] = f2b(tile[tx][ty + i]);
    return;
  }

  if (b < NB_SPLIT + NB_TW1 + NB_TW2) {
    int idx = b - NB_SPLIT - NB_TW1;
    int e = idx >> 12, rem = idx & 4095;
    int by = rem >> 5, bx = rem & 31;
    int r0 = by * 32, c0 = bx * 32;
    const float* src = W2 + (size_t)e * DFF * DM;
    unsigned short* dst = w2t + (size_t)e * DFF * DM;
#pragma unroll
    for (int i = 0; i < 32; i += 8) tile[ty + i][tx] = src[(size_t)(r0 + ty + i) * DM + c0 + tx];
    __syncthreads();
#pragma unroll
    for (int i = 0; i < 32; i += 8) dst[(size_t)(c0 + ty + i) * DFF + r0 + tx] = f2b(tile[tx][ty + i]);
    return;
  }

  {
    int idx = b - NB_SPLIT - NB_TW1 - NB_TW2;
    int by = idx >> 5, bx = idx & 31;
    int r0 = by * 32, c0 = bx * 32;
#pragma unroll
    for (int i = 0; i < 32; i += 8) tile[ty + i][tx] = Wg1[(size_t)(r0 + ty + i) * DM + c0 + tx];
    __syncthreads();
#pragma unroll
    for (int i = 0; i < 32; i += 8) {
      float f = tile[tx][ty + i];
      _Float16 h = (_Float16)f;
      size_t idx2 = (size_t)(c0 + ty + i) * DM + r0 + tx;
      wth[idx2] = h;
      wtl[idx2] = (_Float16)((f - (float)h) * 2048.0f);
    }
  }
}

// ---------------- MFMA router (verified) ----------------
__global__ __launch_bounds__(256) void router_mfma_kernel(
    const _Float16* __restrict__ xh, const _Float16* __restrict__ xl,
    const _Float16* __restrict__ wth, const _Float16* __restrict__ wtl,
    const float* __restrict__ bg1, const float* __restrict__ Wg2,
    float* __restrict__ logits) {
  __shared__ __align__(16) char AB[2][32768];
  __shared__ float lgt[128 * 2 * NE];

  const int tid = threadIdx.x;
  const int lane = tid & 63;
  const int w = tid >> 6;
  const int n0 = blockIdx.x * 128, m0 = blockIdx.y * 128;

  const int r0 = w * 16 + (lane >> 2);
  const int r1 = r0 + 64;
  const int sp = lane & 3;
  const int k0s = (sp ^ ((r0 >> 1) & 3)) * 8;
  const int k1s = (sp ^ ((r1 >> 1) & 3)) * 8;

  const _Float16* gAh0 = xh + (size_t)(m0 + r0) * DM + k0s;
  const _Float16* gAh1 = xh + (size_t)(m0 + r1) * DM + k1s;
  const _Float16* gAl0 = xl + (size_t)(m0 + r0) * DM + k0s;
  const _Float16* gAl1 = xl + (size_t)(m0 + r1) * DM + k1s;
  const _Float16* gBh0 = wth + (size_t)(n0 + r0) * DM + k0s;
  const _Float16* gBh1 = wth + (size_t)(n0 + r1) * DM + k1s;
  const _Float16* gBl0 = wtl + (size_t)(n0 + r0) * DM + k0s;
  const _Float16* gBl1 = wtl + (size_t)(n0 + r1) * DM + k1s;

  const int wr = (w >> 1) * 64, wc = (w & 1) * 64;
  const int l15 = lane & 15, ls = lane >> 4;

  f32x4 zero = {0.f, 0.f, 0.f, 0.f};
  f32x4 acc_hh[4][4], acc_c[4][4];
#pragma unroll
  for (int i = 0; i < 4; i++)
#pragma unroll
    for (int j = 0; j < 4; j++) { acc_hh[i][j] = zero; acc_c[i][j] = zero; }

  auto stage = [&](int buf, int kt) {
    char* b = &AB[buf][0] + w * 1024;
    async16(gAh0 + kt, b);
    async16(gAh1 + kt, b + 4096);
    async16(gAl0 + kt, b + 8192);
    async16(gAl1 + kt, b + 8192 + 4096);
    async16(gBh0 + kt, b + 16384);
    async16(gBh1 + kt, b + 16384 + 4096);
    async16(gBl0 + kt, b + 24576);
    async16(gBl1 + kt, b + 24576 + 4096);
  };
  auto computeTile = [&](int cur) {
    const char* base = &AB[cur][0];
    f16x8 ah[4], bh[4], tmp[4];
#pragma unroll
    for (int i = 0; i < 4; i++) {
      int ar = wr + i * 16 + l15;
      ah[i] = *(const f16x8*)(base + ar * 64 + ((ls ^ ((ar >> 1) & 3)) << 4));
    }
#pragma unroll
    for (int j = 0; j < 4; j++) {
      int br = wc + j * 16 + l15;
      bh[j] = *(const f16x8*)(base + 16384 + br * 64 + ((ls ^ ((br >> 1) & 3)) << 4));
    }
    __builtin_amdgcn_s_setprio(1);
#pragma unroll
    for (int i = 0; i < 4; i++)
#pragma unroll
      for (int j = 0; j < 4; j++)
        acc_hh[i][j] = __builtin_amdgcn_mfma_f32_16x16x32_f16(ah[i], bh[j], acc_hh[i][j], 0, 0, 0);
    __builtin_amdgcn_s_setprio(0);
#pragma unroll
    for (int j = 0; j < 4; j++) {
      int br = wc + j * 16 + l15;
      tmp[j] = *(const f16x8*)(base + 24576 + br * 64 + ((ls ^ ((br >> 1) & 3)) << 4));
    }
    __builtin_amdgcn_s_setprio(1);
#pragma unroll
    for (int i = 0; i < 4; i++)
#pragma unroll
      for (int j = 0; j < 4; j++)
        acc_c[i][j] = __builtin_amdgcn_mfma_f32_16x16x32_f16(ah[i], tmp[j], acc_c[i][j], 0, 0, 0);
    __builtin_amdgcn_s_setprio(0);
#pragma unroll
    for (int i = 0; i < 4; i++) {
      int ar = wr + i * 16 + l15;
      tmp[i] = *(const f16x8*)(base + 8192 + ar * 64 + ((ls ^ ((ar >> 1) & 3)) << 4));
    }
    __builtin_amdgcn_s_setprio(1);
#pragma unroll
    for (int i = 0; i < 4; i++)
#pragma unroll
      for (int j = 0; j < 4; j++)
        acc_c[i][j] = __builtin_amdgcn_mfma_f32_16x16x32_f16(tmp[i], bh[j], acc_c[i][j], 0, 0, 0);
    __builtin_amdgcn_s_setprio(0);
  };

  const int NIT = DM / 32;
  stage(0, 0);
  __syncthreads();
#pragma unroll 2
  for (int t = 0; t < NIT - 1; t++) {
    const int cur = t & 1;
    stage(cur ^ 1, (t + 1) * 32);
    computeTile(cur);
    __syncthreads();
  }
  computeTile((NIT - 1) & 1);

  float w2r[4][8];
  float bias[4];
#pragma unroll
  for (int j = 0; j < 4; j++) {
    int gn = n0 + wc + j * 16 + l15;
    bias[j] = bg1[gn];
    float4 u = *(const float4*)(Wg2 + (size_t)gn * NE);
    float4 v = *(const float4*)(Wg2 + (size_t)gn * NE + 4);
    w2r[j][0] = u.x; w2r[j][1] = u.y; w2r[j][2] = u.z; w2r[j][3] = u.w;
    w2r[j][4] = v.x; w2r[j][5] = v.y; w2r[j][6] = v.z; w2r[j][7] = v.w;
  }
  const float inv2k = 1.0f / 2048.0f;
  const int half = wc >> 6;
  const bool b3 = (l15 & 8) != 0, b2 = (l15 & 4) != 0, b1 = (l15 & 2) != 0;
#pragma unroll
  for (int i = 0; i < 4; i++) {
#pragma unroll
    for (int r = 0; r < 4; r++) {
      float s[8] = {0.f, 0.f, 0.f, 0.f, 0.f, 0.f, 0.f, 0.f};
#pragma unroll
      for (int j = 0; j < 4; j++) {
        float hv = tanh_fast(acc_hh[i][j][r] + acc_c[i][j][r] * inv2k + bias[j]);
#pragma unroll
        for (int e = 0; e < NE; e++) s[e] = fmaf(hv, w2r[j][e], s[e]);
      }
      float t4_[4], t2_[2], t1_;
#pragma unroll
      for (int q = 0; q < 4; q++) {
        float snd = b3 ? s[q] : s[q + 4];
        float rcv = __shfl_xor(snd, 8);
        t4_[q] = (b3 ? s[q + 4] : s[q]) + rcv;
      }
#pragma unroll
      for (int q = 0; q < 2; q++) {
        float snd = b2 ? t4_[q] : t4_[q + 2];
        float rcv = __shfl_xor(snd, 4);
        t2_[q] = (b2 ? t4_[q + 2] : t4_[q]) + rcv;
      }
      {
        float snd = b1 ? t2_[0] : t2_[1];
        float rcv = __shfl_xor(snd, 2);
        t1_ = (b1 ? t2_[1] : t2_[0]) + rcv;
      }
      t1_ += __shfl_xor(t1_, 1);
      int m = wr + i * 16 + ls * 4 + r;
      if (!(l15 & 1)) lgt[m * (2 * NE) + half * NE + (l15 >> 1)] = t1_;
    }
  }
  __syncthreads();
#pragma unroll
  for (int q = 0; q < 4; q++) {
    int idx = tid * 4 + q;
    int m = idx >> 3, e = idx & 7;
    float v = lgt[m * (2 * NE) + e] + lgt[m * (2 * NE) + NE + e];
    atomicAdd(&logits[(size_t)(m0 + m) * NE + e], v);
  }
}

// ---------------- top-2 over 8 logits per token ----------------
__global__ __launch_bounds__(256) void topk_small_kernel(
    const float* __restrict__ logits, int* __restrict__ tIdx, float* __restrict__ tGate,
    int* __restrict__ counts) {
  __shared__ int lc[NE];
  const int tid = threadIdx.x;
  if (tid < NE) lc[tid] = 0;
  __syncthreads();
  int t = blockIdx.x * 256 + tid;
  float p[NE];
  float4 p0 = *(const float4*)(logits + (size_t)t * NE);
  float4 p1 = *(const float4*)(logits + (size_t)t * NE + 4);
  p[0] = p0.x; p[1] = p0.y; p[2] = p0.z; p[3] = p0.w;
  p[4] = p1.x; p[5] = p1.y; p[6] = p1.z; p[7] = p1.w;
  float v1 = -1e30f, v2 = -1e30f; int i1 = 0, i2 = 1;
#pragma unroll
  for (int e = 0; e < NE; e++) {
    float v = p[e];
    if (v > v1) { v2 = v1; i2 = i1; v1 = v; i1 = e; }
    else if (v > v2) { v2 = v; i2 = e; }
  }
  float mx = v1;
  float s = 0.f;
#pragma unroll
  for (int e = 0; e < NE; e++) s += __expf(p[e] - mx);
  float inv = 1.f / s;
  float g1 = __expf(p[i1] - mx) * inv;
  float g2 = __expf(p[i2] - mx) * inv;
  float den = 1.f / (g1 + g2 + 1e-6f);
  tIdx[2 * t] = i1; tIdx[2 * t + 1] = i2;
  tGate[2 * t] = g1 * den; tGate[2 * t + 1] = g2 * den;
  atomicAdd(&lc[i1], 1);
  atomicAdd(&lc[i2], 1);
  __syncthreads();
  if (tid < NE) atomicAdd(&counts[tid], lc[tid]);
}

// ---------------- prefix sums + tile descriptors (single thread) ----------------
__global__ void build_tiles_kernel(const int* __restrict__ counts, int* __restrict__ offsets,
                                   int4* __restrict__ desc, int* __restrict__ nTiles) {
  if (threadIdx.x != 0 || blockIdx.x != 0) return;
  int off = 0, nt = 0;
  for (int e = 0; e < NE; e++) {
    offsets[e] = off;
    int c = counts[e];
    if (c < 0) c = 0;
    if (c > 2 * T_TOK) c = 2 * T_TOK;
    for (int r = 0; r < c && nt < MAX_TILES; r += 128) {
      int v = c - r; if (v > 128) v = 128;
      desc[nt++] = make_int4(e, off + r, v, 0);
    }
    off += c;
    if (off > 2 * T_TOK) off = 2 * T_TOK;
  }
  offsets[NE] = off;
  *nTiles = nt;
}

// ---------------- scatter tokens into expert-grouped lists ----------------
__global__ void scatter_kernel(const int* __restrict__ tIdx, const float* __restrict__ tGate,
                               const int* __restrict__ offsets, int* __restrict__ fill,
                               int* __restrict__ tokList, float* __restrict__ gateList) {
  int id = blockIdx.x * blockDim.x + threadIdx.x;
  if (id >= 2 * T_TOK) return;
  int e = tIdx[id] & 7;
  int pos = atomicAdd(&fill[e], 1);
  int row = offsets[e] + pos;
  if (row < 0 || row >= 2 * T_TOK) return;
  tokList[row] = id >> 1;
  gateList[row] = tGate[id];
}

// ---------------- FFN1: h = gelu(gather(xb) @ W1_e), BK=32, 3-buf counted-vmcnt, XCD-affine ----------------
__global__ __launch_bounds__(256) void ffn1_kernel(
    const unsigned short* __restrict__ xb, const unsigned short* __restrict__ w1t,
    const int* __restrict__ tokList, const int4* __restrict__ desc,
    const int* __restrict__ nTiles, unsigned short* __restrict__ h) {
  const int g = blockIdx.x;
  const int tileIdx = (g & 7) * TPX + ((g >> 3) % TPX);
  const int nb = g / (8 * TPX);
  if (tileIdx >= *nTiles) return;
  int4 d = desc[tileIdx];
  const int e = d.x, rowStart = d.y, valid = d.z;
  const int n0 = nb * 128;

  __shared__ __align__(16) char AB[3][16384];  // 3-deep pipeline, 48 KB

  const int tid = threadIdx.x;
  const int lane = tid & 63;
  const int w = tid >> 6;

  const int r0 = w * 16 + (lane >> 2);
  const int r1 = r0 + 64;
  const int sp = lane & 3;
  const int k0s = (sp ^ ((r0 >> 1) & 3)) * 8;
  const int k1s = (sp ^ ((r1 >> 1) & 3)) * 8;

  const unsigned short* gA0 = xb + (size_t)(tokList[rowStart + r0] & (T_TOK - 1)) * DM + k0s;
  const unsigned short* gA1 = xb + (size_t)(tokList[rowStart + r1] & (T_TOK - 1)) * DM + k1s;
  const unsigned short* gB0 = w1t + ((size_t)e * DFF + n0 + r0) * DM + k0s;
  const unsigned short* gB1 = w1t + ((size_t)e * DFF + n0 + r1) * DM + k1s;

  const int wr = (w >> 1) * 64, wc = (w & 1) * 64;
  const int l15 = lane & 15, ls = lane >> 4;

  f32x4 zero = {0.f, 0.f, 0.f, 0.f};
  f32x4 acc[4][4];
#pragma unroll
  for (int i = 0; i < 4; i++)
#pragma unroll
    for (int j = 0; j < 4; j++) acc[i][j] = zero;

  auto stage = [&](int buf, int kt) {  // 4 loads per wave per call
    char* dA = &AB[buf][0] + w * 1024;
    char* dB = dA + 8192;
    async16(gA0 + kt, dA);
    async16(gA1 + kt, dA + 4096);
    async16(gB0 + kt, dB);
    async16(gB1 + kt, dB + 4096);
  };
  auto computeTile = [&](int cur) {
    const char* rA = &AB[cur][0];
    const char* rB = rA + 8192;
    bf16x8 af[4], bfv[4];
#pragma unroll
    for (int i = 0; i < 4; i++) {
      int ar = wr + i * 16 + l15;
      af[i] = *(const bf16x8*)(rA + ar * 64 + ((ls ^ ((ar >> 1) & 3)) << 4));
    }
#pragma unroll
    for (int j = 0; j < 4; j++) {
      int br = wc + j * 16 + l15;
      bfv[j] = *(const bf16x8*)(rB + br * 64 + ((ls ^ ((br >> 1) & 3)) << 4));
    }
    __builtin_amdgcn_s_setprio(1);
#pragma unroll
    for (int i = 0; i < 4; i++)
#pragma unroll
      for (int j = 0; j < 4; j++)
        acc[i][j] = __builtin_amdgcn_mfma_f32_16x16x32_bf16(af[i], bfv[j], acc[i][j], 0, 0, 0);
    __builtin_amdgcn_s_setprio(0);
  };

  const int NIT = DM / 32;
  stage(0, 0);
  stage(1, 32);
  int cur = 0, stg = 2;
  for (int t = 0; t < NIT; t++) {
    if (t < NIT - 1) asm volatile("s_waitcnt vmcnt(4)" ::: "memory");
    else             asm volatile("s_waitcnt vmcnt(0)" ::: "memory");
    __builtin_amdgcn_s_barrier();
    __builtin_amdgcn_sched_barrier(0);
    if (t < NIT - 2) {
      stage(stg, (t + 2) * 32);
      stg = (stg == 2) ? 0 : stg + 1;
    }
    computeTile(cur);
    cur = (cur == 2) ? 0 : cur + 1;
  }

#pragma unroll
  for (int i = 0; i < 4; i++) {
#pragma unroll
    for (int r = 0; r < 4; r++) {
      int m = wr + i * 16 + ls * 4 + r;
      if (m < valid) {
        size_t base = (size_t)(rowStart + m) * DFF + n0 + wc;
#pragma unroll
        for (int j = 0; j < 4; j++) {
          h[base + j * 16 + l15] = f2b(gelu_fast(acc[i][j][r]));
        }
      }
    }
  }
}

// ---------------- FFN2: y += gate * (h @ W2_e), BK=32, 3-buf counted-vmcnt, XCD-affine ----------------
__global__ __launch_bounds__(256) void ffn2_kernel(
    const unsigned short* __restrict__ h, const unsigned short* __restrict__ w2t,
    const int* __restrict__ tokList, const float* __restrict__ gateList,
    const int4* __restrict__ desc, const int* __restrict__ nTiles,
    float* __restrict__ y) {
  const int g = blockIdx.x;
  const int tileIdx = (g & 7) * TPX + ((g >> 3) % TPX);
  const int nb = g / (8 * TPX);
  if (tileIdx >= *nTiles) return;
  int4 d = desc[tileIdx];
  const int e = d.x, rowStart = d.y, valid = d.z;
  const int n0 = nb * 128;

  __shared__ __align__(16) char AB[3][16384];

  const int tid = threadIdx.x;
  const int lane = tid & 63;
  const int w = tid >> 6;

  const int r0 = w * 16 + (lane >> 2);
  const int r1 = r0 + 64;
  const int sp = lane & 3;
  const int k0s = (sp ^ ((r0 >> 1) & 3)) * 8;
  const int k1s = (sp ^ ((r1 >> 1) & 3)) * 8;

  const unsigned short* gA0 = h + (size_t)(rowStart + r0) * DFF + k0s;
  const unsigned short* gA1 = h + (size_t)(rowStart + r1) * DFF + k1s;
  const unsigned short* gB0 = w2t + ((size_t)e * DM + n0 + r0) * DFF + k0s;
  const unsigned short* gB1 = w2t + ((size_t)e * DM + n0 + r1) * DFF + k1s;

  const int wr = (w >> 1) * 64, wc = (w & 1) * 64;
  const int l15 = lane & 15, ls = lane >> 4;

  f32x4 zero = {0.f, 0.f, 0.f, 0.f};
  f32x4 acc[4][4];
#pragma unroll
  for (int i = 0; i < 4; i++)
#pragma unroll
    for (int j = 0; j < 4; j++) acc[i][j] = zero;

  auto stage = [&](int buf, int kt) {
    char* dA = &AB[buf][0] + w * 1024;
    char* dB = dA + 8192;
    async16(gA0 + kt, dA);
    async16(gA1 + kt, dA + 4096);
    async16(gB0 + kt, dB);
    async16(gB1 + kt, dB + 4096);
  };
  auto computeTile = [&](int cur) {
    const char* rA = &AB[cur][0];
    const char* rB = rA + 8192;
    bf16x8 af[4], bfv[4];
#pragma unroll
    for (int i = 0; i < 4; i++) {
      int ar = wr + i * 16 + l15;
      af[i] = *(const bf16x8*)(rA + ar * 64 + ((ls ^ ((ar >> 1) & 3)) << 4));
    }
#pragma unroll
    for (int j = 0; j < 4; j++) {
      int br = wc + j * 16 + l15;
      bfv[j] = *(const bf16x8*)(rB + br * 64 + ((ls ^ ((br >> 1) & 3)) << 4));
    }
    __builtin_amdgcn_s_setprio(1);
#pragma unroll
    for (int i = 0; i < 4; i++)
#pragma unroll
      for (int j = 0; j < 4; j++)
        acc[i][j] = __builtin_amdgcn_mfma_f32_16x16x32_bf16(af[i], bfv[j], acc[i][j], 0, 0, 0);
    __builtin_amdgcn_s_setprio(0);
  };

  const int NIT = DFF / 32;
  stage(0, 0);
  stage(1, 32);
  int cur = 0, stg = 2;
  for (int t = 0; t < NIT; t++) {
    if (t < NIT - 1) asm volatile("s_waitcnt vmcnt(4)" ::: "memory");
    else             asm volatile("s_waitcnt vmcnt(0)" ::: "memory");
    __builtin_amdgcn_s_barrier();
    __builtin_amdgcn_sched_barrier(0);
    if (t < NIT - 2) {
      stage(stg, (t + 2) * 32);
      stg = (stg == 2) ? 0 : stg + 1;
    }
    computeTile(cur);
    cur = (cur == 2) ? 0 : cur + 1;
  }

#pragma unroll
  for (int i = 0; i < 4; i++) {
#pragma unroll
    for (int r = 0; r < 4; r++) {
      int m = wr + i * 16 + ls * 4 + r;
      if (m < valid) {
        int row = rowStart + m;
        int tok = tokList[row] & (T_TOK - 1);
        float g2 = gateList[row];
        float* yr = y + (size_t)tok * DM + n0 + wc;
#pragma unroll
        for (int j = 0; j < 4; j++) {
          atomicAdd(&yr[j * 16 + l15], g2 * acc[i][j][r]);
        }
      }
    }
  }
}

// ---------------- host launch ----------------
extern "C" void kernel_launch(void* const* d_in, const int* in_sizes, int n_in,
                              void* d_out, int out_size, void* d_ws, size_t ws_size,
                              hipStream_t stream) {
  const float* x   = (const float*)d_in[0];
  const float* Wg1 = (const float*)d_in[1];
  const float* bg1 = (const float*)d_in[2];
  const float* Wg2 = (const float*)d_in[3];
  const float* W1  = (const float*)d_in[4];
  const float* W2  = (const float*)d_in[5];
  float* y = (float*)d_out;
  char* ws = (char*)d_ws;

  const size_t SZ_W1T = (size_t)NE * DFF * DM * 2;
  const size_t OFF_W1T = 0;
  const size_t OFF_W2T = OFF_W1T + SZ_W1T;
  const size_t OFF_XB  = OFF_W2T + SZ_W1T;
  const size_t OFF_H   = OFF_XB + (size_t)T_TOK * DM * 2;
  const size_t OFF_TOK = OFF_H + (size_t)HROWS * DFF * 2;
  const size_t OFF_GATE = OFF_TOK + (size_t)HROWS * 4;
  const size_t OFF_TIDX = OFF_GATE + (size_t)HROWS * 4;
  const size_t OFF_TG   = OFF_TIDX + (size_t)2 * T_TOK * 4;
  const size_t OFF_LOG  = OFF_TG + (size_t)2 * T_TOK * 4;
  const size_t OFF_META = OFF_LOG + (size_t)T_TOK * NE * 4;
  const size_t NEED = OFF_META + 4096;

  const size_t OFF_XH  = OFF_H;
  const size_t OFF_XL  = OFF_XH + (size_t)T_TOK * DM * 2;
  const size_t OFF_WTH = OFF_XL + (size_t)T_TOK * DM * 2;
  const size_t OFF_WTL = OFF_WTH + (size_t)DM * DM * 2;

  if (ws_size < NEED) {
    hipMemsetAsync(d_out, 0, (size_t)out_size * 4, stream);
    return;
  }

  unsigned short* w1t = (unsigned short*)(ws + OFF_W1T);
  unsigned short* w2t = (unsigned short*)(ws + OFF_W2T);
  unsigned short* xb  = (unsigned short*)(ws + OFF_XB);
  unsigned short* h   = (unsigned short*)(ws + OFF_H);
  _Float16* xh        = (_Float16*)(ws + OFF_XH);
  _Float16* xl        = (_Float16*)(ws + OFF_XL);
  _Float16* wth       = (_Float16*)(ws + OFF_WTH);
  _Float16* wtl       = (_Float16*)(ws + OFF_WTL);
  int* tokList        = (int*)(ws + OFF_TOK);
  float* gateList     = (float*)(ws + OFF_GATE);
  int* tIdx           = (int*)(ws + OFF_TIDX);
  float* tGate        = (float*)(ws + OFF_TG);
  float* logits       = (float*)(ws + OFF_LOG);
  int* meta           = (int*)(ws + OFF_META);
  int* counts         = (int*)(ws + OFF_META);
  int* fill           = (int*)(ws + OFF_META + 32);
  int* offsets        = (int*)(ws + OFF_META + 64);
  int* nTiles         = (int*)(ws + OFF_META + 128);
  int4* desc          = (int4*)(ws + OFF_META + 160);

  prep_all_kernel<<<dim3(NB_PREP), dim3(256), 0, stream>>>(
      x, xb, xh, xl, W1, w1t, W2, w2t, Wg1, wth, wtl, y, out_size, logits, meta);

  router_mfma_kernel<<<dim3(DM / 128, T_TOK / 128), dim3(256), 0, stream>>>(xh, xl, wth, wtl,
                                                                            bg1, Wg2, logits);
  topk_small_kernel<<<dim3(T_TOK / 256), dim3(256), 0, stream>>>(logits, tIdx, tGate, counts);
  build_tiles_kernel<<<dim3(1), dim3(64), 0, stream>>>(counts, offsets, desc, nTiles);
  scatter_kernel<<<dim3((2 * T_TOK) / 256), dim3(256), 0, stream>>>(tIdx, tGate, offsets, fill,
                                                                    tokList, gateList);

  ffn1_kernel<<<dim3((DFF / 128) * MAX_TILES), dim3(256), 0, stream>>>(xb, w1t, tokList, desc,
                                                                       nTiles, h);
  ffn2_kernel<<<dim3((DM / 128) * MAX_TILES), dim3(256), 0, stream>>>(h, w2t, tokList, gateList,
                                                                      desc, nTiles, y);
}

// Round 15
// 662.581 us; speedup vs baseline: 1.1022x; 1.0189x over previous
//
#include <hip/hip_runtime.h>
#include <hip/hip_bf16.h>
#include <math.h>

#define T_TOK 8192
#define DM 1024
#define DFF 4096
#define NE 8
#define HROWS 16512
#define MAX_TILES 136
#define TPX 17  // tiles per XCD class (MAX_TILES/8)

// fused-prep block ranges
#define NB_SPLIT (T_TOK * DM / 4 / 256)          // 8192
#define NB_TW1 ((DFF / 32) * (DM / 32) * NE)     // 32768
#define NB_TW2 ((DM / 32) * (DFF / 32) * NE)     // 32768
#define NB_TSW ((DM / 32) * (DM / 32))           // 1024
#define NB_ZY 8193                               // zero y + loss (out_size floats)
#define NB_ZLOG 64                               // zero logits (65536 floats)
#define NB_ZMETA 1
#define NB_PREP (NB_SPLIT + NB_TW1 + NB_TW2 + NB_TSW + NB_ZY + NB_ZLOG + NB_ZMETA)

typedef __attribute__((ext_vector_type(8))) short bf16x8;
typedef __attribute__((ext_vector_type(4))) float f32x4;
typedef __attribute__((ext_vector_type(8))) _Float16 f16x8;
typedef __attribute__((ext_vector_type(4))) _Float16 f16x4;

__device__ __forceinline__ void async16(const void* g, void* l) {
  __builtin_amdgcn_global_load_lds((const __attribute__((address_space(1))) void*)g,
                                   (__attribute__((address_space(3))) void*)l, 16, 0, 0);
}

__device__ __forceinline__ unsigned short f2b(float f) {
  __hip_bfloat16 h = __float2bfloat16(f);
  return *reinterpret_cast<unsigned short*>(&h);
}

__device__ __forceinline__ float tanh_fast(float z) {
  return 1.f - 2.f / (__expf(2.f * z) + 1.f);
}

__device__ __forceinline__ float gelu_fast(float v) {
  float u = v + 0.044715f * v * v * v;
  return v / (1.f + __expf(-1.5957691216057308f * u));
}

// ---------------- fused preprocessing + zero-init ----------------
__global__ __launch_bounds__(256) void prep_all_kernel(
    const float* __restrict__ x, unsigned short* __restrict__ xb,
    _Float16* __restrict__ xh, _Float16* __restrict__ xl,
    const float* __restrict__ W1, unsigned short* __restrict__ w1t,
    const float* __restrict__ W2, unsigned short* __restrict__ w2t,
    const float* __restrict__ Wg1, _Float16* __restrict__ wth, _Float16* __restrict__ wtl,
    float* __restrict__ y, int out_size, float* __restrict__ logits, int* __restrict__ meta) {
  __shared__ float tile[32][33];
  const int b = blockIdx.x;
  const int tid = threadIdx.x;

  if (b < NB_SPLIT) {
    int i = b * 256 + tid;
    float4 v = reinterpret_cast<const float4*>(x)[i];
    ushort4 ob;
    f16x4 oh, ol;
    float f, hf;
    f = v.x; oh[0] = (_Float16)f; hf = (float)oh[0]; ol[0] = (_Float16)((f - hf) * 2048.0f); ob.x = f2b(f);
    f = v.y; oh[1] = (_Float16)f; hf = (float)oh[1]; ol[1] = (_Float16)((f - hf) * 2048.0f); ob.y = f2b(f);
    f = v.z; oh[2] = (_Float16)f; hf = (float)oh[2]; ol[2] = (_Float16)((f - hf) * 2048.0f); ob.z = f2b(f);
    f = v.w; oh[3] = (_Float16)f; hf = (float)oh[3]; ol[3] = (_Float16)((f - hf) * 2048.0f); ob.w = f2b(f);
    reinterpret_cast<ushort4*>(xb)[i] = ob;
    reinterpret_cast<f16x4*>(xh)[i] = oh;
    reinterpret_cast<f16x4*>(xl)[i] = ol;
    return;
  }

  if (b >= NB_SPLIT + NB_TW1 + NB_TW2 + NB_TSW) {
    int zb = b - (NB_SPLIT + NB_TW1 + NB_TW2 + NB_TSW);
    if (zb < NB_ZY) {
      int i4 = zb * 256 + tid;
      if ((i4 + 1) * 4 <= out_size) {
        reinterpret_cast<float4*>(y)[i4] = make_float4(0.f, 0.f, 0.f, 0.f);
      } else {
#pragma unroll
        for (int k = 0; k < 4; k++) {
          int idx = i4 * 4 + k;
          if (idx < out_size) y[idx] = 0.f;
        }
      }
    } else if (zb < NB_ZY + NB_ZLOG) {
      int i4 = (zb - NB_ZY) * 256 + tid;
      reinterpret_cast<float4*>(logits)[i4] = make_float4(0.f, 0.f, 0.f, 0.f);
    } else {
      if (tid < 16) meta[tid] = 0;
    }
    return;
  }

  const int tx = tid & 31, ty = tid >> 5;  // (32,8)

  if (b < NB_SPLIT + NB_TW1) {
    int idx = b - NB_SPLIT;
    int e = idx >> 12, rem = idx & 4095;
    int by = rem >> 7, bx = rem & 127;
    int r0 = by * 32, c0 = bx * 32;
    const float* src = W1 + (size_t)e * DM * DFF;
    unsigned short* dst = w1t + (size_t)e * DM * DFF;
#pragma unroll
    for (int i = 0; i < 32; i += 8) tile[ty + i][tx] = src[(size_t)(r0 + ty + i) * DFF + c0 + tx];
    __syncthreads();
#pragma unroll
    for (int i = 0; i < 32; i += 8) dst[(size_t)(c0 + ty + i) * DM + r0 + tx] = f2b(tile[tx][ty + i]);
    return;
  }

  if (b < NB_SPLIT + NB_TW1 + NB_TW2) {
    int idx = b - NB_SPLIT - NB_TW1;
    int e = idx >> 12, rem = idx & 4095;
    int by = rem >> 5, bx = rem & 31;
    int r0 = by * 32, c0 = bx * 32;
    const float* src = W2 + (size_t)e * DFF * DM;
    unsigned short* dst = w2t + (size_t)e * DFF * DM;
#pragma unroll
    for (int i = 0; i < 32; i += 8) tile[ty + i][tx] = src[(size_t)(r0 + ty + i) * DM + c0 + tx];
    __syncthreads();
#pragma unroll
    for (int i = 0; i < 32; i += 8) dst[(size_t)(c0 + ty + i) * DFF + r0 + tx] = f2b(tile[tx][ty + i]);
    return;
  }

  {
    int idx = b - NB_SPLIT - NB_TW1 - NB_TW2;
    int by = idx >> 5, bx = idx & 31;
    int r0 = by * 32, c0 = bx * 32;
#pragma unroll
    for (int i = 0; i < 32; i += 8) tile[ty + i][tx] = Wg1[(size_t)(r0 + ty + i) * DM + c0 + tx];
    __syncthreads();
#pragma unroll
    for (int i = 0; i < 32; i += 8) {
      float f = tile[tx][ty + i];
      _Float16 h = (_Float16)f;
      size_t idx2 = (size_t)(c0 + ty + i) * DM + r0 + tx;
      wth[idx2] = h;
      wtl[idx2] = (_Float16)((f - (float)h) * 2048.0f);
    }
  }
}

// ---------------- MFMA router (verified) ----------------
__global__ __launch_bounds__(256) void router_mfma_kernel(
    const _Float16* __restrict__ xh, const _Float16* __restrict__ xl,
    const _Float16* __restrict__ wth, const _Float16* __restrict__ wtl,
    const float* __restrict__ bg1, const float* __restrict__ Wg2,
    float* __restrict__ logits) {
  __shared__ __align__(16) char AB[2][32768];
  __shared__ float lgt[128 * 2 * NE];

  const int tid = threadIdx.x;
  const int lane = tid & 63;
  const int w = tid >> 6;
  const int n0 = blockIdx.x * 128, m0 = blockIdx.y * 128;

  const int r0 = w * 16 + (lane >> 2);
  const int r1 = r0 + 64;
  const int sp = lane & 3;
  const int k0s = (sp ^ ((r0 >> 1) & 3)) * 8;
  const int k1s = (sp ^ ((r1 >> 1) & 3)) * 8;

  const _Float16* gAh0 = xh + (size_t)(m0 + r0) * DM + k0s;
  const _Float16* gAh1 = xh + (size_t)(m0 + r1) * DM + k1s;
  const _Float16* gAl0 = xl + (size_t)(m0 + r0) * DM + k0s;
  const _Float16* gAl1 = xl + (size_t)(m0 + r1) * DM + k1s;
  const _Float16* gBh0 = wth + (size_t)(n0 + r0) * DM + k0s;
  const _Float16* gBh1 = wth + (size_t)(n0 + r1) * DM + k1s;
  const _Float16* gBl0 = wtl + (size_t)(n0 + r0) * DM + k0s;
  const _Float16* gBl1 = wtl + (size_t)(n0 + r1) * DM + k1s;

  const int wr = (w >> 1) * 64, wc = (w & 1) * 64;
  const int l15 = lane & 15, ls = lane >> 4;

  f32x4 zero = {0.f, 0.f, 0.f, 0.f};
  f32x4 acc_hh[4][4], acc_c[4][4];
#pragma unroll
  for (int i = 0; i < 4; i++)
#pragma unroll
    for (int j = 0; j < 4; j++) { acc_hh[i][j] = zero; acc_c[i][j] = zero; }

  auto stage = [&](int buf, int kt) {
    char* b = &AB[buf][0] + w * 1024;
    async16(gAh0 + kt, b);
    async16(gAh1 + kt, b + 4096);
    async16(gAl0 + kt, b + 8192);
    async16(gAl1 + kt, b + 8192 + 4096);
    async16(gBh0 + kt, b + 16384);
    async16(gBh1 + kt, b + 16384 + 4096);
    async16(gBl0 + kt, b + 24576);
    async16(gBl1 + kt, b + 24576 + 4096);
  };
  auto computeTile = [&](int cur) {
    const char* base = &AB[cur][0];
    f16x8 ah[4], bh[4], tmp[4];
#pragma unroll
    for (int i = 0; i < 4; i++) {
      int ar = wr + i * 16 + l15;
      ah[i] = *(const f16x8*)(base + ar * 64 + ((ls ^ ((ar >> 1) & 3)) << 4));
    }
#pragma unroll
    for (int j = 0; j < 4; j++) {
      int br = wc + j * 16 + l15;
      bh[j] = *(const f16x8*)(base + 16384 + br * 64 + ((ls ^ ((br >> 1) & 3)) << 4));
    }
    __builtin_amdgcn_s_setprio(1);
#pragma unroll
    for (int i = 0; i < 4; i++)
#pragma unroll
      for (int j = 0; j < 4; j++)
        acc_hh[i][j] = __builtin_amdgcn_mfma_f32_16x16x32_f16(ah[i], bh[j], acc_hh[i][j], 0, 0, 0);
    __builtin_amdgcn_s_setprio(0);
#pragma unroll
    for (int j = 0; j < 4; j++) {
      int br = wc + j * 16 + l15;
      tmp[j] = *(const f16x8*)(base + 24576 + br * 64 + ((ls ^ ((br >> 1) & 3)) << 4));
    }
    __builtin_amdgcn_s_setprio(1);
#pragma unroll
    for (int i = 0; i < 4; i++)
#pragma unroll
      for (int j = 0; j < 4; j++)
        acc_c[i][j] = __builtin_amdgcn_mfma_f32_16x16x32_f16(ah[i], tmp[j], acc_c[i][j], 0, 0, 0);
    __builtin_amdgcn_s_setprio(0);
#pragma unroll
    for (int i = 0; i < 4; i++) {
      int ar = wr + i * 16 + l15;
      tmp[i] = *(const f16x8*)(base + 8192 + ar * 64 + ((ls ^ ((ar >> 1) & 3)) << 4));
    }
    __builtin_amdgcn_s_setprio(1);
#pragma unroll
    for (int i = 0; i < 4; i++)
#pragma unroll
      for (int j = 0; j < 4; j++)
        acc_c[i][j] = __builtin_amdgcn_mfma_f32_16x16x32_f16(tmp[i], bh[j], acc_c[i][j], 0, 0, 0);
    __builtin_amdgcn_s_setprio(0);
  };

  const int NIT = DM / 32;
  stage(0, 0);
  __syncthreads();
#pragma unroll 2
  for (int t = 0; t < NIT - 1; t++) {
    const int cur = t & 1;
    stage(cur ^ 1, (t + 1) * 32);
    computeTile(cur);
    __syncthreads();
  }
  computeTile((NIT - 1) & 1);

  float w2r[4][8];
  float bias[4];
#pragma unroll
  for (int j = 0; j < 4; j++) {
    int gn = n0 + wc + j * 16 + l15;
    bias[j] = bg1[gn];
    float4 u = *(const float4*)(Wg2 + (size_t)gn * NE);
    float4 v = *(const float4*)(Wg2 + (size_t)gn * NE + 4);
    w2r[j][0] = u.x; w2r[j][1] = u.y; w2r[j][2] = u.z; w2r[j][3] = u.w;
    w2r[j][4] = v.x; w2r[j][5] = v.y; w2r[j][6] = v.z; w2r[j][7] = v.w;
  }
  const float inv2k = 1.0f / 2048.0f;
  const int half = wc >> 6;
  const bool b3 = (l15 & 8) != 0, b2 = (l15 & 4) != 0, b1 = (l15 & 2) != 0;
#pragma unroll
  for (int i = 0; i < 4; i++) {
#pragma unroll
    for (int r = 0; r < 4; r++) {
      float s[8] = {0.f, 0.f, 0.f, 0.f, 0.f, 0.f, 0.f, 0.f};
#pragma unroll
      for (int j = 0; j < 4; j++) {
        float hv = tanh_fast(acc_hh[i][j][r] + acc_c[i][j][r] * inv2k + bias[j]);
#pragma unroll
        for (int e = 0; e < NE; e++) s[e] = fmaf(hv, w2r[j][e], s[e]);
      }
      float t4_[4], t2_[2], t1_;
#pragma unroll
      for (int q = 0; q < 4; q++) {
        float snd = b3 ? s[q] : s[q + 4];
        float rcv = __shfl_xor(snd, 8);
        t4_[q] = (b3 ? s[q + 4] : s[q]) + rcv;
      }
#pragma unroll
      for (int q = 0; q < 2; q++) {
        float snd = b2 ? t4_[q] : t4_[q + 2];
        float rcv = __shfl_xor(snd, 4);
        t2_[q] = (b2 ? t4_[q + 2] : t4_[q]) + rcv;
      }
      {
        float snd = b1 ? t2_[0] : t2_[1];
        float rcv = __shfl_xor(snd, 2);
        t1_ = (b1 ? t2_[1] : t2_[0]) + rcv;
      }
      t1_ += __shfl_xor(t1_, 1);
      int m = wr + i * 16 + ls * 4 + r;
      if (!(l15 & 1)) lgt[m * (2 * NE) + half * NE + (l15 >> 1)] = t1_;
    }
  }
  __syncthreads();
#pragma unroll
  for (int q = 0; q < 4; q++) {
    int idx = tid * 4 + q;
    int m = idx >> 3, e = idx & 7;
    float v = lgt[m * (2 * NE) + e] + lgt[m * (2 * NE) + NE + e];
    atomicAdd(&logits[(size_t)(m0 + m) * NE + e], v);
  }
}

// ---------------- top-2 over 8 logits per token ----------------
__global__ __launch_bounds__(256) void topk_small_kernel(
    const float* __restrict__ logits, int* __restrict__ tIdx, float* __restrict__ tGate,
    int* __restrict__ counts) {
  __shared__ int lc[NE];
  const int tid = threadIdx.x;
  if (tid < NE) lc[tid] = 0;
  __syncthreads();
  int t = blockIdx.x * 256 + tid;
  float p[NE];
  float4 p0 = *(const float4*)(logits + (size_t)t * NE);
  float4 p1 = *(const float4*)(logits + (size_t)t * NE + 4);
  p[0] = p0.x; p[1] = p0.y; p[2] = p0.z; p[3] = p0.w;
  p[4] = p1.x; p[5] = p1.y; p[6] = p1.z; p[7] = p1.w;
  float v1 = -1e30f, v2 = -1e30f; int i1 = 0, i2 = 1;
#pragma unroll
  for (int e = 0; e < NE; e++) {
    float v = p[e];
    if (v > v1) { v2 = v1; i2 = i1; v1 = v; i1 = e; }
    else if (v > v2) { v2 = v; i2 = e; }
  }
  float mx = v1;
  float s = 0.f;
#pragma unroll
  for (int e = 0; e < NE; e++) s += __expf(p[e] - mx);
  float inv = 1.f / s;
  float g1 = __expf(p[i1] - mx) * inv;
  float g2 = __expf(p[i2] - mx) * inv;
  float den = 1.f / (g1 + g2 + 1e-6f);
  tIdx[2 * t] = i1; tIdx[2 * t + 1] = i2;
  tGate[2 * t] = g1 * den; tGate[2 * t + 1] = g2 * den;
  atomicAdd(&lc[i1], 1);
  atomicAdd(&lc[i2], 1);
  __syncthreads();
  if (tid < NE) atomicAdd(&counts[tid], lc[tid]);
}

// ---------------- prefix sums + tile descriptors (single thread) ----------------
__global__ void build_tiles_kernel(const int* __restrict__ counts, int* __restrict__ offsets,
                                   int4* __restrict__ desc, int* __restrict__ nTiles) {
  if (threadIdx.x != 0 || blockIdx.x != 0) return;
  int off = 0, nt = 0;
  for (int e = 0; e < NE; e++) {
    offsets[e] = off;
    int c = counts[e];
    if (c < 0) c = 0;
    if (c > 2 * T_TOK) c = 2 * T_TOK;
    for (int r = 0; r < c && nt < MAX_TILES; r += 128) {
      int v = c - r; if (v > 128) v = 128;
      desc[nt++] = make_int4(e, off + r, v, 0);
    }
    off += c;
    if (off > 2 * T_TOK) off = 2 * T_TOK;
  }
  offsets[NE] = off;
  *nTiles = nt;
}

// ---------------- scatter tokens into expert-grouped lists ----------------
__global__ void scatter_kernel(const int* __restrict__ tIdx, const float* __restrict__ tGate,
                               const int* __restrict__ offsets, int* __restrict__ fill,
                               int* __restrict__ tokList, float* __restrict__ gateList) {
  int id = blockIdx.x * blockDim.x + threadIdx.x;
  if (id >= 2 * T_TOK) return;
  int e = tIdx[id] & 7;
  int pos = atomicAdd(&fill[e], 1);
  int row = offsets[e] + pos;
  if (row < 0 || row >= 2 * T_TOK) return;
  tokList[row] = id >> 1;
  gateList[row] = tGate[id];
}

// ---------------- FFN1: 128x256 tile, 8 waves (512 thr), BK=32, 3-buf depth-2, XCD-affine ----------------
__global__ __launch_bounds__(512) void ffn1_kernel(
    const unsigned short* __restrict__ xb, const unsigned short* __restrict__ w1t,
    const int* __restrict__ tokList, const int4* __restrict__ desc,
    const int* __restrict__ nTiles, unsigned short* __restrict__ h) {
  const int g = blockIdx.x;
  const int tileIdx = (g & 7) * TPX + ((g >> 3) % TPX);
  const int nb = g / (8 * TPX);  // [0,16): 256-wide n-block
  if (tileIdx >= *nTiles) return;
  int4 d = desc[tileIdx];
  const int e = d.x, rowStart = d.y, valid = d.z;
  const int n0 = nb * 256;

  // per buf: A[128][64B] @0 (8KB), B[256][64B] @8192 (16KB); 3 bufs = 72KB -> 2 blocks/CU
  __shared__ __align__(16) char AB[3][24576];

  const int tid = threadIdx.x;
  const int lane = tid & 63;
  const int w = tid >> 6;  // [0,8)

  const int sub = lane >> 2;       // 16 rows per load-group
  const int sp = lane & 3;
  // A: wave w stages rows [w*16, w*16+16)
  const int rA = w * 16 + sub;
  const int ksA = (sp ^ ((rA >> 1) & 3)) * 8;
  // B: wave w stages rows [w*32, w*32+32) in two loads
  const int rB0 = w * 32 + sub;
  const int rB1 = rB0 + 16;
  const int ksB0 = (sp ^ ((rB0 >> 1) & 3)) * 8;
  const int ksB1 = (sp ^ ((rB1 >> 1) & 3)) * 8;

  const unsigned short* gA = xb + (size_t)(tokList[rowStart + rA] & (T_TOK - 1)) * DM + ksA;
  const unsigned short* gB0 = w1t + ((size_t)e * DFF + n0 + rB0) * DM + ksB0;
  const unsigned short* gB1 = w1t + ((size_t)e * DFF + n0 + rB1) * DM + ksB1;

  const int wr = (w >> 2) * 64, wc = (w & 3) * 64;
  const int l15 = lane & 15, ls = lane >> 4;

  f32x4 zero = {0.f, 0.f, 0.f, 0.f};
  f32x4 acc[4][4];
#pragma unroll
  for (int i = 0; i < 4; i++)
#pragma unroll
    for (int j = 0; j < 4; j++) acc[i][j] = zero;

  auto stage = [&](int buf, int kt) {  // 3 loads per wave per call
    char* base = &AB[buf][0];
    async16(gA + kt, base + w * 1024);                    // A rows w*16..: dest row-major
    async16(gB0 + kt, base + 8192 + w * 2048);            // B rows w*32..w*32+16
    async16(gB1 + kt, base + 8192 + w * 2048 + 1024);     // B rows w*32+16..w*32+32
  };
  auto computeTile = [&](int cur) {
    const char* rAb = &AB[cur][0];
    const char* rBb = rAb + 8192;
    bf16x8 af[4], bfv[4];
#pragma unroll
    for (int i = 0; i < 4; i++) {
      int ar = wr + i * 16 + l15;
      af[i] = *(const bf16x8*)(rAb + ar * 64 + ((ls ^ ((ar >> 1) & 3)) << 4));
    }
#pragma unroll
    for (int j = 0; j < 4; j++) {
      int br = wc + j * 16 + l15;
      bfv[j] = *(const bf16x8*)(rBb + br * 64 + ((ls ^ ((br >> 1) & 3)) << 4));
    }
    __builtin_amdgcn_s_setprio(1);
#pragma unroll
    for (int i = 0; i < 4; i++)
#pragma unroll
      for (int j = 0; j < 4; j++)
        acc[i][j] = __builtin_amdgcn_mfma_f32_16x16x32_bf16(af[i], bfv[j], acc[i][j], 0, 0, 0);
    __builtin_amdgcn_s_setprio(0);
  };

  const int NIT = DM / 32;
  stage(0, 0);
  stage(1, 32);
  int cur = 0, stg = 2;
  for (int t = 0; t < NIT; t++) {
    if (t < NIT - 1) asm volatile("s_waitcnt vmcnt(3)" ::: "memory");
    else             asm volatile("s_waitcnt vmcnt(0)" ::: "memory");
    __builtin_amdgcn_s_barrier();
    __builtin_amdgcn_sched_barrier(0);
    if (t < NIT - 2) {
      stage(stg, (t + 2) * 32);
      stg = (stg == 2) ? 0 : stg + 1;
    }
    computeTile(cur);
    cur = (cur == 2) ? 0 : cur + 1;
  }

#pragma unroll
  for (int i = 0; i < 4; i++) {
#pragma unroll
    for (int r = 0; r < 4; r++) {
      int m = wr + i * 16 + ls * 4 + r;
      if (m < valid) {
        size_t base = (size_t)(rowStart + m) * DFF + n0 + wc;
#pragma unroll
        for (int j = 0; j < 4; j++) {
          h[base + j * 16 + l15] = f2b(gelu_fast(acc[i][j][r]));
        }
      }
    }
  }
}

// ---------------- FFN2: 128x256 tile, 8 waves, K-split x2, 3-buf depth-2, XCD-affine ----------------
__global__ __launch_bounds__(512) void ffn2_kernel(
    const unsigned short* __restrict__ h, const unsigned short* __restrict__ w2t,
    const int* __restrict__ tokList, const float* __restrict__ gateList,
    const int4* __restrict__ desc, const int* __restrict__ nTiles,
    float* __restrict__ y) {
  const int g = blockIdx.x;
  const int tileIdx = (g & 7) * TPX + ((g >> 3) % TPX);
  const int q = g / (8 * TPX);      // [0,8)
  const int nb = q & 3;             // 256-wide n-block
  const int kslice = q >> 2;        // K-split half
  if (tileIdx >= *nTiles) return;
  int4 d = desc[tileIdx];
  const int e = d.x, rowStart = d.y, valid = d.z;
  const int n0 = nb * 256;
  const int kb = kslice * (DFF / 2);

  __shared__ __align__(16) char AB[3][24576];

  const int tid = threadIdx.x;
  const int lane = tid & 63;
  const int w = tid >> 6;

  const int sub = lane >> 2;
  const int sp = lane & 3;
  const int rA = w * 16 + sub;
  const int ksA = (sp ^ ((rA >> 1) & 3)) * 8;
  const int rB0 = w * 32 + sub;
  const int rB1 = rB0 + 16;
  const int ksB0 = (sp ^ ((rB0 >> 1) & 3)) * 8;
  const int ksB1 = (sp ^ ((rB1 >> 1) & 3)) * 8;

  const unsigned short* gA = h + (size_t)(rowStart + rA) * DFF + kb + ksA;
  const unsigned short* gB0 = w2t + ((size_t)e * DM + n0 + rB0) * DFF + kb + ksB0;
  const unsigned short* gB1 = w2t + ((size_t)e * DM + n0 + rB1) * DFF + kb + ksB1;

  const int wr = (w >> 2) * 64, wc = (w & 3) * 64;
  const int l15 = lane & 15, ls = lane >> 4;

  f32x4 zero = {0.f, 0.f, 0.f, 0.f};
  f32x4 acc[4][4];
#pragma unroll
  for (int i = 0; i < 4; i++)
#pragma unroll
    for (int j = 0; j < 4; j++) acc[i][j] = zero;

  auto stage = [&](int buf, int kt) {
    char* base = &AB[buf][0];
    async16(gA + kt, base + w * 1024);
    async16(gB0 + kt, base + 8192 + w * 2048);
    async16(gB1 + kt, base + 8192 + w * 2048 + 1024);
  };
  auto computeTile = [&](int cur) {
    const char* rAb = &AB[cur][0];
    const char* rBb = rAb + 8192;
    bf16x8 af[4], bfv[4];
#pragma unroll
    for (int i = 0; i < 4; i++) {
      int ar = wr + i * 16 + l15;
      af[i] = *(const bf16x8*)(rAb + ar * 64 + ((ls ^ ((ar >> 1) & 3)) << 4));
    }
#pragma unroll
    for (int j = 0; j < 4; j++) {
      int br = wc + j * 16 + l15;
      bfv[j] = *(const bf16x8*)(rBb + br * 64 + ((ls ^ ((br >> 1) & 3)) << 4));
    }
    __builtin_amdgcn_s_setprio(1);
#pragma unroll
    for (int i = 0; i < 4; i++)
#pragma unroll
      for (int j = 0; j < 4; j++)
        acc[i][j] = __builtin_amdgcn_mfma_f32_16x16x32_bf16(af[i], bfv[j], acc[i][j], 0, 0, 0);
    __builtin_amdgcn_s_setprio(0);
  };

  const int NIT = (DFF / 2) / 32;  // 64
  stage(0, 0);
  stage(1, 32);
  int cur = 0, stg = 2;
  for (int t = 0; t < NIT; t++) {
    if (t < NIT - 1) asm volatile("s_waitcnt vmcnt(3)" ::: "memory");
    else             asm volatile("s_waitcnt vmcnt(0)" ::: "memory");
    __builtin_amdgcn_s_barrier();
    __builtin_amdgcn_sched_barrier(0);
    if (t < NIT - 2) {
      stage(stg, (t + 2) * 32);
      stg = (stg == 2) ? 0 : stg + 1;
    }
    computeTile(cur);
    cur = (cur == 2) ? 0 : cur + 1;
  }

#pragma unroll
  for (int i = 0; i < 4; i++) {
#pragma unroll
    for (int r = 0; r < 4; r++) {
      int m = wr + i * 16 + ls * 4 + r;
      if (m < valid) {
        int row = rowStart + m;
        int tok = tokList[row] & (T_TOK - 1);
        float g2 = gateList[row];
        float* yr = y + (size_t)tok * DM + n0 + wc;
#pragma unroll
        for (int j = 0; j < 4; j++) {
          atomicAdd(&yr[j * 16 + l15], g2 * acc[i][j][r]);
        }
      }
    }
  }
}

// ---------------- host launch ----------------
extern "C" void kernel_launch(void* const* d_in, const int* in_sizes, int n_in,
                              void* d_out, int out_size, void* d_ws, size_t ws_size,
                              hipStream_t stream) {
  const float* x   = (const float*)d_in[0];
  const float* Wg1 = (const float*)d_in[1];
  const float* bg1 = (const float*)d_in[2];
  const float* Wg2 = (const float*)d_in[3];
  const float* W1  = (const float*)d_in[4];
  const float* W2  = (const float*)d_in[5];
  float* y = (float*)d_out;
  char* ws = (char*)d_ws;

  const size_t SZ_W1T = (size_t)NE * DFF * DM * 2;
  const size_t OFF_W1T = 0;
  const size_t OFF_W2T = OFF_W1T + SZ_W1T;
  const size_t OFF_XB  = OFF_W2T + SZ_W1T;
  const size_t OFF_H   = OFF_XB + (size_t)T_TOK * DM * 2;
  const size_t OFF_TOK = OFF_H + (size_t)HROWS * DFF * 2;
  const size_t OFF_GATE = OFF_TOK + (size_t)HROWS * 4;
  const size_t OFF_TIDX = OFF_GATE + (size_t)HROWS * 4;
  const size_t OFF_TG   = OFF_TIDX + (size_t)2 * T_TOK * 4;
  const size_t OFF_LOG  = OFF_TG + (size_t)2 * T_TOK * 4;
  const size_t OFF_META = OFF_LOG + (size_t)T_TOK * NE * 4;
  const size_t NEED = OFF_META + 4096;

  const size_t OFF_XH  = OFF_H;
  const size_t OFF_XL  = OFF_XH + (size_t)T_TOK * DM * 2;
  const size_t OFF_WTH = OFF_XL + (size_t)T_TOK * DM * 2;
  const size_t OFF_WTL = OFF_WTH + (size_t)DM * DM * 2;

  if (ws_size < NEED) {
    hipMemsetAsync(d_out, 0, (size_t)out_size * 4, stream);
    return;
  }

  unsigned short* w1t = (unsigned short*)(ws + OFF_W1T);
  unsigned short* w2t = (unsigned short*)(ws + OFF_W2T);
  unsigned short* xb  = (unsigned short*)(ws + OFF_XB);
  unsigned short* h   = (unsigned short*)(ws + OFF_H);
  _Float16* xh        = (_Float16*)(ws + OFF_XH);
  _Float16* xl        = (_Float16*)(ws + OFF_XL);
  _Float16* wth       = (_Float16*)(ws + OFF_WTH);
  _Float16* wtl       = (_Float16*)(ws + OFF_WTL);
  int* tokList        = (int*)(ws + OFF_TOK);
  float* gateList     = (float*)(ws + OFF_GATE);
  int* tIdx           = (int*)(ws + OFF_TIDX);
  float* tGate        = (float*)(ws + OFF_TG);
  float* logits       = (float*)(ws + OFF_LOG);
  int* meta           = (int*)(ws + OFF_META);
  int* counts         = (int*)(ws + OFF_META);
  int* fill           = (int*)(ws + OFF_META + 32);
  int* offsets        = (int*)(ws + OFF_META + 64);
  int* nTiles         = (int*)(ws + OFF_META + 128);
  int4* desc          = (int4*)(ws + OFF_META + 160);

  prep_all_kernel<<<dim3(NB_PREP), dim3(256), 0, stream>>>(
      x, xb, xh, xl, W1, w1t, W2, w2t, Wg1, wth, wtl, y, out_size, logits, meta);

  router_mfma_kernel<<<dim3(DM / 128, T_TOK / 128), dim3(256), 0, stream>>>(xh, xl, wth, wtl,
                                                                            bg1, Wg2, logits);
  topk_small_kernel<<<dim3(T_TOK / 256), dim3(256), 0, stream>>>(logits, tIdx, tGate, counts);
  build_tiles_kernel<<<dim3(1), dim3(64), 0, stream>>>(counts, offsets, desc, nTiles);
  scatter_kernel<<<dim3((2 * T_TOK) / 256), dim3(256), 0, stream>>>(tIdx, tGate, offsets, fill,
                                                                    tokList, gateList);

  // ffn1: 16 n-blocks of 256 ; ffn2: 4 n-blocks of 256 x 2 K-slices ; 512-thread blocks
  ffn1_kernel<<<dim3(16 * 8 * TPX), dim3(512), 0, stream>>>(xb, w1t, tokList, desc, nTiles, h);
  ffn2_kernel<<<dim3(8 * 8 * TPX), dim3(512), 0, stream>>>(h, w2t, tokList, gateList, desc,
                                                           nTiles, y);
}